// Round 11
// baseline (28.984 us; speedup 1.0000x reference)
//
#include <hip/hip_runtime.h>
#include <math.h>

#define EPS_REG 1e-6f
#define MIN_EIG_F 1e-4f
#define RB 8        // rows per chunk / per fused block

// ---------- 3x3 helpers ----------

__device__ __forceinline__ void sym_inv3(const float m[3][3], float o[3][3]) {
    float c00 = m[1][1]*m[2][2] - m[1][2]*m[2][1];
    float c01 = m[1][2]*m[2][0] - m[1][0]*m[2][2];
    float c02 = m[1][0]*m[2][1] - m[1][1]*m[2][0];
    float det = m[0][0]*c00 + m[0][1]*c01 + m[0][2]*c02;
    float inv = 1.0f / det;
    o[0][0] = c00*inv;
    o[1][0] = c01*inv;
    o[2][0] = c02*inv;
    o[0][1] = (m[0][2]*m[2][1]-m[0][1]*m[2][2])*inv;
    o[1][1] = (m[0][0]*m[2][2]-m[0][2]*m[2][0])*inv;
    o[2][1] = (m[0][1]*m[2][0]-m[0][0]*m[2][1])*inv;
    o[0][2] = (m[0][1]*m[1][2]-m[0][2]*m[1][1])*inv;
    o[1][2] = (m[0][2]*m[1][0]-m[0][0]*m[1][2])*inv;
    o[2][2] = (m[0][0]*m[1][1]-m[0][1]*m[1][0])*inv;
}

__device__ __forceinline__ void rodrigues(float w0, float w1, float w2, float R[3][3]) {
    float th2 = w0*w0 + w1*w1 + w2*w2;
    float th = sqrtf(th2);
    float a, b;
    if (th < 1e-4f) { a = 1.0f - th2*(1.0f/6.0f); b = 0.5f - th2*(1.0f/24.0f); }
    else            { a = sinf(th)/th;            b = (1.0f - cosf(th))/th2; }
    R[0][0] = 1.0f + b*(w0*w0 - th2); R[0][1] = -a*w2 + b*w0*w1;        R[0][2] =  a*w1 + b*w0*w2;
    R[1][0] =  a*w2 + b*w0*w1;        R[1][1] = 1.0f + b*(w1*w1 - th2); R[1][2] = -a*w0 + b*w1*w2;
    R[2][0] = -a*w1 + b*w0*w2;        R[2][1] =  a*w0 + b*w1*w2;        R[2][2] = 1.0f + b*(w2*w2 - th2);
}

__device__ __forceinline__ void jrot(float A[3][3], float V[3][3], int p, int q) {
    float apq = A[p][q];
    if (fabsf(apq) < 1e-20f) return;
    float theta = (A[q][q] - A[p][p]) / (2.0f * apq);
    float t = 1.0f / (fabsf(theta) + sqrtf(1.0f + theta*theta));
    if (theta < 0.0f) t = -t;
    float c = 1.0f / sqrtf(1.0f + t*t);
    float s = t * c;
    int r = 3 - p - q;
    float apq_t = t*apq;
    A[p][p] -= apq_t;
    A[q][q] += apq_t;
    A[p][q] = 0.0f; A[q][p] = 0.0f;
    float arp = A[r][p], arq = A[r][q];
    A[r][p] = c*arp - s*arq; A[p][r] = A[r][p];
    A[r][q] = s*arp + c*arq; A[q][r] = A[r][q];
    #pragma unroll
    for (int k = 0; k < 3; k++) {
        float vkp = V[k][p], vkq = V[k][q];
        V[k][p] = c*vkp - s*vkq;
        V[k][q] = s*vkp + c*vkq;
    }
}

__device__ __forceinline__ void compute_S_from(const float* sq9, const float* ph3, float sv[6]) {
    float m[3][3], lq[3][3];
    #pragma unroll
    for (int i = 0; i < 3; i++)
        #pragma unroll
        for (int j = 0; j < 3; j++) m[i][j] = sq9[i*3 + j];
    m[0][0] += EPS_REG; m[1][1] += EPS_REG; m[2][2] += EPS_REG;
    sym_inv3(m, lq);
    float R[3][3];
    rodrigues(ph3[0], ph3[1], ph3[2], R);
    float U[3][3];
    #pragma unroll
    for (int i = 0; i < 3; i++)
        #pragma unroll
        for (int j = 0; j < 3; j++)
            U[i][j] = lq[i][0]*R[0][j] + lq[i][1]*R[1][j] + lq[i][2]*R[2][j];
    sv[0] = R[0][0]*U[0][0] + R[1][0]*U[1][0] + R[2][0]*U[2][0];
    sv[1] = R[0][0]*U[0][1] + R[1][0]*U[1][1] + R[2][0]*U[2][1];
    sv[2] = R[0][0]*U[0][2] + R[1][0]*U[1][2] + R[2][0]*U[2][2];
    sv[3] = R[0][1]*U[0][1] + R[1][1]*U[1][1] + R[2][1]*U[2][1];
    sv[4] = R[0][1]*U[0][2] + R[1][1]*U[1][2] + R[2][1]*U[2][2];
    sv[5] = R[0][2]*U[0][2] + R[1][2]*U[1][2] + R[2][2]*U[2][2];
}

__device__ __forceinline__ void finalize_point(const float* sq9, const float* sp9,
                                               const float* ph3, const float* tp,
                                               float cs, float* o1, float* o2) {
    float m[3][3], lp[3][3], lq[3][3];
    #pragma unroll
    for (int i = 0; i < 3; i++)
        #pragma unroll
        for (int j = 0; j < 3; j++) m[i][j] = sq9[i*3 + j];
    m[0][0] += EPS_REG; m[1][1] += EPS_REG; m[2][2] += EPS_REG;
    sym_inv3(m, lq);
    #pragma unroll
    for (int i = 0; i < 3; i++)
        #pragma unroll
        for (int j = 0; j < 3; j++) m[i][j] = sp9[i*3 + j];
    m[0][0] += EPS_REG; m[1][1] += EPS_REG; m[2][2] += EPS_REG;
    sym_inv3(m, lp);

    float R[3][3];
    rodrigues(ph3[0], ph3[1], ph3[2], R);

    float Tm[3][3] = {{tp[0],tp[1],tp[2]},{tp[1],tp[3],tp[4]},{tp[2],tp[4],tp[5]}};

    float U[3][3], M[3][3];
    #pragma unroll
    for (int ii = 0; ii < 3; ii++)
        #pragma unroll
        for (int jj = 0; jj < 3; jj++)
            U[ii][jj] = R[ii][0]*Tm[0][jj] + R[ii][1]*Tm[1][jj] + R[ii][2]*Tm[2][jj];
    #pragma unroll
    for (int ii = 0; ii < 3; ii++)
        #pragma unroll
        for (int jj = 0; jj < 3; jj++) {
            float min_ij = U[ii][0]*R[jj][0] + U[ii][1]*R[jj][1] + U[ii][2]*R[jj][2];
            M[ii][jj] = lp[ii][jj] + min_ij + cs * lq[ii][jj];
        }
    float A[3][3];
    #pragma unroll
    for (int ii = 0; ii < 3; ii++)
        #pragma unroll
        for (int jj = 0; jj < 3; jj++) A[ii][jj] = 0.5f * (M[ii][jj] + M[jj][ii]);

    float V[3][3] = {{1,0,0},{0,1,0},{0,0,1}};
    #pragma unroll
    for (int sweep = 0; sweep < 6; sweep++) {
        jrot(A, V, 0, 1);
        jrot(A, V, 0, 2);
        jrot(A, V, 1, 2);
    }
    float w0 = fmaxf(A[0][0], MIN_EIG_F);
    float w1 = fmaxf(A[1][1], MIN_EIG_F);
    float w2 = fmaxf(A[2][2], MIN_EIG_F);
    float iw0 = 1.0f/w0, iw1 = 1.0f/w1, iw2 = 1.0f/w2;

    #pragma unroll
    for (int ii = 0; ii < 3; ii++)
        #pragma unroll
        for (int jj = 0; jj < 3; jj++) {
            o1[ii*3 + jj] = V[ii][0]*w0*V[jj][0] + V[ii][1]*w1*V[jj][1] + V[ii][2]*w2*V[jj][2];
            o2[ii*3 + jj] = V[ii][0]*iw0*V[jj][0] + V[ii][1]*iw1*V[jj][1] + V[ii][2]*iw2*V[jj][2];
        }
}

// ---------- kernel 1: per-point S -> SoA planes ----------
__global__ __launch_bounds__(64) void precompute_S_kernel(
        const float* __restrict__ Sq,
        const float* __restrict__ phi,
        float* __restrict__ Splanes,
        int BN) {
    __shared__ float sq_s[576];
    __shared__ float ph_s[192];
    int tid = threadIdx.x;
    int p0 = blockIdx.x * 64;

    const float4* src = (const float4*)(Sq + (size_t)p0 * 9);
    #pragma unroll
    for (int i = tid; i < 144; i += 64) ((float4*)sq_s)[i] = src[i];
    const float4* psrc = (const float4*)(phi + (size_t)p0 * 3);
    if (tid < 48) ((float4*)ph_s)[tid] = psrc[tid];
    __syncthreads();

    float sv[6];
    compute_S_from(sq_s + tid*9, ph_s + tid*3, sv);
    #pragma unroll
    for (int c = 0; c < 6; c++)
        Splanes[(size_t)c * BN + p0 + tid] = sv[c];
}

// ---------- kernel 2: one pass over beta; one 1024-col tile per block ----------
// grid = (BN/RB) * ctiles, 256 thr, 24.8 KB LDS, VGPR capped for 4 blocks/CU.
//   T2[ct][row][6]  per-tile row-sum partials (finalize adds tiles)
//   partial[b][chunk][col]  column partials (block owns disjoint col range)
__global__ __launch_bounds__(256, 4) void fused_beta_kernel(
        const float* __restrict__ beta,
        const float* __restrict__ Splanes,
        float* __restrict__ T2,       // [ctiles][BN][6]
        float* __restrict__ partial,  // B * (N/RB) * N
        int B, int N, int BN) {
    int tid = threadIdx.x;
    int ctiles = N >> 10;
    int rg = blockIdx.x / ctiles;
    int ct = blockIdx.x - rg * ctiles;
    int grow0 = rg * RB;
    int b = grow0 / N;
    int chunksPerB = N / RB;
    int chunk = (grow0 - b * N) / RB;
    int c0 = (ct << 10) + 4 * tid;

    // all loads issued up front (14 float4 in flight)
    float4 s[6], w[RB];
    #pragma unroll
    for (int c = 0; c < 6; c++)
        s[c] = *(const float4*)(Splanes + (size_t)c * BN + (size_t)b * N + c0);
    #pragma unroll
    for (int r = 0; r < RB; r++)
        w[r] = *(const float4*)(beta + (size_t)(grow0 + r) * N + c0);

    float csum0 = 0.f, csum1 = 0.f, csum2 = 0.f, csum3 = 0.f;
    #pragma unroll
    for (int r = 0; r < RB; r++) {
        csum0 += w[r].x; csum1 += w[r].y; csum2 += w[r].z; csum3 += w[r].w;
    }
    *(float4*)(partial + ((size_t)b * chunksPerB + chunk) * N + c0) =
        make_float4(csum0, csum1, csum2, csum3);

    float acc[RB][6];
    #pragma unroll
    for (int r = 0; r < RB; r++)
        #pragma unroll
        for (int c = 0; c < 6; c++)
            acc[r][c] = w[r].x*s[c].x + w[r].y*s[c].y + w[r].z*s[c].z + w[r].w*s[c].w;

    // two-stage LDS transpose reduction (24 KB; verified in R10's coop run)
    __shared__ float red[128][48];
    __shared__ float red2[4][48];
    if (tid < 128) {
        #pragma unroll
        for (int r = 0; r < RB; r++)
            #pragma unroll
            for (int c = 0; c < 6; c++)
                red[tid][r * 6 + c] = acc[r][c];
    }
    __syncthreads();
    if (tid >= 128) {
        #pragma unroll
        for (int r = 0; r < RB; r++)
            #pragma unroll
            for (int c = 0; c < 6; c++)
                red[tid - 128][r * 6 + c] += acc[r][c];   // exclusive row
    }
    __syncthreads();
    if (tid < 192) {
        int v = tid % 48, grp = tid / 48;   // 4 groups x 32 rows
        float sum = 0.0f;
        #pragma unroll 8
        for (int r = 0; r < 32; r++) sum += red[grp * 32 + r][v];
        red2[grp][v] = sum;
    }
    __syncthreads();
    if (tid < 48) {
        float v = red2[0][tid] + red2[1][tid] + red2[2][tid] + red2[3][tid];
        T2[((size_t)ct * BN + grow0) * 6 + tid] = v;
    }
}

// ---------- kernel 3: finalize (BN/32 blocks, 32 pts, 256 thr) ----------
__global__ __launch_bounds__(256) void finalize_kernel(
        const float* __restrict__ Sp,
        const float* __restrict__ Sq,
        const float* __restrict__ phi,
        const float* __restrict__ T2,      // [ctiles][BN][6]
        const float* __restrict__ partial, // B*(N/RB)*N
        float* __restrict__ out,
        int B, int N) {
    int tid  = threadIdx.x;
    int p0   = blockIdx.x * 32;
    int BN   = B * N;
    int b    = p0 / N;
    int i0   = p0 - b * N;
    int chunks = N / RB;
    int ctiles = N >> 10;

    __shared__ float4 redc[32][8];
    __shared__ float sp_s[288], sq_s[288], ph_s[96], t_s[192];
    __shared__ float o1_s[288], o2_s[288];

    // float4 column-sum: 32 groups x (chunks/32) chunks, 8 col-quads
    {
        int m = tid & 7;
        int g = tid >> 3;
        int cpg = chunks / 32;
        float4 a = make_float4(0.f, 0.f, 0.f, 0.f);
        const float4* pp = (const float4*)(partial + ((size_t)b * chunks + g * cpg) * N + i0) + m;
        int stepq = N >> 2;
        for (int k = 0; k < cpg; k++) {
            float4 v = *pp; pp += stepq;
            a.x += v.x; a.y += v.y; a.z += v.z; a.w += v.w;
        }
        redc[g][m] = a;
    }
    // stage per-point inputs; T = sum of per-tile partials
    {
        const float4* s1 = (const float4*)(Sp + (size_t)p0 * 9);
        const float4* s2 = (const float4*)(Sq + (size_t)p0 * 9);
        if (tid < 72) { ((float4*)sp_s)[tid] = s1[tid]; ((float4*)sq_s)[tid] = s2[tid]; }
        const float4* s3 = (const float4*)(phi + (size_t)p0 * 3);
        if (tid < 24) ((float4*)ph_s)[tid] = s3[tid];
        if (tid < 48) {
            float4 a = make_float4(0.f, 0.f, 0.f, 0.f);
            for (int ct = 0; ct < ctiles; ct++) {
                float4 v = ((const float4*)(T2 + ((size_t)ct * BN + p0) * 6))[tid];
                a.x += v.x; a.y += v.y; a.z += v.z; a.w += v.w;
            }
            ((float4*)t_s)[tid] = a;
        }
    }
    __syncthreads();

    if (tid < 32) {
        float cs = 0.0f;
        #pragma unroll
        for (int g = 0; g < 32; g++) {
            const float* rc = (const float*)&redc[g][tid >> 2];
            cs += rc[tid & 3];
        }
        finalize_point(sq_s + tid*9, sp_s + tid*9, ph_s + tid*3,
                       t_s + tid*6, cs, o1_s + tid*9, o2_s + tid*9);
    }
    __syncthreads();

    float4* d1 = (float4*)(out + (size_t)p0 * 9);
    float4* d2 = (float4*)(out + (size_t)BN * 9 + (size_t)p0 * 9);
    if (tid < 72) { d1[tid] = ((float4*)o1_s)[tid]; d2[tid] = ((float4*)o2_s)[tid]; }
}

extern "C" void kernel_launch(void* const* d_in, const int* in_sizes, int n_in,
                              void* d_out, int out_size, void* d_ws, size_t ws_size,
                              hipStream_t stream) {
    const float* Sp   = (const float*)d_in[0];
    const float* Sq   = (const float*)d_in[1];
    const float* phi  = (const float*)d_in[2];
    const float* beta = (const float*)d_in[3];

    int BN = in_sizes[2] / 3;                 // B*N
    int N  = (int)((long long)in_sizes[3] / BN);
    int B  = BN / N;
    int ctiles = N >> 10;                     // 1024-col tiles

    float* ws = (float*)d_ws;
    float* Splanes = ws;                                  // 6*BN
    float* T2      = Splanes + (size_t)BN * 6;            // ctiles*6*BN
    float* partial = T2 + (size_t)ctiles * BN * 6;        // B*(N/RB)*N

    float* outf = (float*)d_out;

    precompute_S_kernel<<<BN / 64, 64, 0, stream>>>(Sq, phi, Splanes, BN);

    fused_beta_kernel<<<(BN / RB) * ctiles, 256, 0, stream>>>(
        beta, Splanes, T2, partial, B, N, BN);

    finalize_kernel<<<BN / 32, 256, 0, stream>>>(Sp, Sq, phi, T2, partial, outf, B, N);
}

// Round 12
// 25.878 us; speedup vs baseline: 1.1200x; 1.1200x over previous
//
#include <hip/hip_runtime.h>
#include <math.h>

#define EPS_REG 1e-6f
#define MIN_EIG_F 1e-4f
#define RB 8        // rows per block in fused beta pass

// ---------- 3x3 helpers ----------

__device__ __forceinline__ void sym_inv3(const float m[3][3], float o[3][3]) {
    float c00 = m[1][1]*m[2][2] - m[1][2]*m[2][1];
    float c01 = m[1][2]*m[2][0] - m[1][0]*m[2][2];
    float c02 = m[1][0]*m[2][1] - m[1][1]*m[2][0];
    float det = m[0][0]*c00 + m[0][1]*c01 + m[0][2]*c02;
    float inv = 1.0f / det;
    o[0][0] = c00*inv;
    o[1][0] = c01*inv;
    o[2][0] = c02*inv;
    o[0][1] = (m[0][2]*m[2][1]-m[0][1]*m[2][2])*inv;
    o[1][1] = (m[0][0]*m[2][2]-m[0][2]*m[2][0])*inv;
    o[2][1] = (m[0][1]*m[2][0]-m[0][0]*m[2][1])*inv;
    o[0][2] = (m[0][1]*m[1][2]-m[0][2]*m[1][1])*inv;
    o[1][2] = (m[0][2]*m[1][0]-m[0][0]*m[1][2])*inv;
    o[2][2] = (m[0][0]*m[1][1]-m[0][1]*m[1][0])*inv;
}

__device__ __forceinline__ void rodrigues(float w0, float w1, float w2, float R[3][3]) {
    float th2 = w0*w0 + w1*w1 + w2*w2;
    float th = sqrtf(th2);
    float a, b;
    if (th < 1e-4f) { a = 1.0f - th2*(1.0f/6.0f); b = 0.5f - th2*(1.0f/24.0f); }
    else            { a = sinf(th)/th;            b = (1.0f - cosf(th))/th2; }
    R[0][0] = 1.0f + b*(w0*w0 - th2); R[0][1] = -a*w2 + b*w0*w1;        R[0][2] =  a*w1 + b*w0*w2;
    R[1][0] =  a*w2 + b*w0*w1;        R[1][1] = 1.0f + b*(w1*w1 - th2); R[1][2] = -a*w0 + b*w1*w2;
    R[2][0] = -a*w1 + b*w0*w2;        R[2][1] =  a*w0 + b*w1*w2;        R[2][2] = 1.0f + b*(w2*w2 - th2);
}

__device__ __forceinline__ void jrot(float A[3][3], float V[3][3], int p, int q) {
    float apq = A[p][q];
    if (fabsf(apq) < 1e-20f) return;
    float theta = (A[q][q] - A[p][p]) / (2.0f * apq);
    float t = 1.0f / (fabsf(theta) + sqrtf(1.0f + theta*theta));
    if (theta < 0.0f) t = -t;
    float c = 1.0f / sqrtf(1.0f + t*t);
    float s = t * c;
    int r = 3 - p - q;
    float apq_t = t*apq;
    A[p][p] -= apq_t;
    A[q][q] += apq_t;
    A[p][q] = 0.0f; A[q][p] = 0.0f;
    float arp = A[r][p], arq = A[r][q];
    A[r][p] = c*arp - s*arq; A[p][r] = A[r][p];
    A[r][q] = s*arp + c*arq; A[q][r] = A[r][q];
    #pragma unroll
    for (int k = 0; k < 3; k++) {
        float vkp = V[k][p], vkq = V[k][q];
        V[k][p] = c*vkp - s*vkq;
        V[k][q] = s*vkp + c*vkq;
    }
}

// ---------- kernel 1: per-point S = R^T Lq R -> SoA planes ----------
__global__ __launch_bounds__(64) void precompute_S_kernel(
        const float* __restrict__ Sq,
        const float* __restrict__ phi,
        float* __restrict__ Splanes,
        int BN) {
    __shared__ float sq_s[576];
    __shared__ float ph_s[192];
    int tid = threadIdx.x;
    int p0 = blockIdx.x * 64;

    const float4* src = (const float4*)(Sq + (size_t)p0 * 9);
    #pragma unroll
    for (int i = tid; i < 144; i += 64) ((float4*)sq_s)[i] = src[i];
    const float4* psrc = (const float4*)(phi + (size_t)p0 * 3);
    if (tid < 48) ((float4*)ph_s)[tid] = psrc[tid];
    __syncthreads();

    float m[3][3], lq[3][3];
    #pragma unroll
    for (int i = 0; i < 3; i++)
        #pragma unroll
        for (int j = 0; j < 3; j++) m[i][j] = sq_s[tid*9 + i*3 + j];
    m[0][0] += EPS_REG; m[1][1] += EPS_REG; m[2][2] += EPS_REG;
    sym_inv3(m, lq);

    float R[3][3];
    rodrigues(ph_s[tid*3], ph_s[tid*3+1], ph_s[tid*3+2], R);

    float U[3][3];
    #pragma unroll
    for (int i = 0; i < 3; i++)
        #pragma unroll
        for (int j = 0; j < 3; j++)
            U[i][j] = lq[i][0]*R[0][j] + lq[i][1]*R[1][j] + lq[i][2]*R[2][j];
    float sv[6];
    sv[0] = R[0][0]*U[0][0] + R[1][0]*U[1][0] + R[2][0]*U[2][0];
    sv[1] = R[0][0]*U[0][1] + R[1][0]*U[1][1] + R[2][0]*U[2][1];
    sv[2] = R[0][0]*U[0][2] + R[1][0]*U[1][2] + R[2][0]*U[2][2];
    sv[3] = R[0][1]*U[0][1] + R[1][1]*U[1][1] + R[2][1]*U[2][1];
    sv[4] = R[0][1]*U[0][2] + R[1][1]*U[1][2] + R[2][1]*U[2][2];
    sv[5] = R[0][2]*U[0][2] + R[1][2]*U[1][2] + R[2][2]*U[2][2];
    #pragma unroll
    for (int c = 0; c < 6; c++)
        Splanes[(size_t)c * BN + p0 + tid] = sv[c];
}

// ---------- kernel 2 (fused): one pass over beta, 2-tile straight-line ----------
__device__ __forceinline__ void beta_tile(
        const float* __restrict__ beta,
        const float* __restrict__ Splanes,
        float* __restrict__ partial,
        int grow0, int b, int N, int BN,
        int chunksPerB, int chunk, int c0,
        float acc[RB][6]) {
    float4 s[6];
    #pragma unroll
    for (int c = 0; c < 6; c++)
        s[c] = *(const float4*)(Splanes + (size_t)c * BN + (size_t)b * N + c0);
    float4 w[RB];
    #pragma unroll
    for (int r = 0; r < RB; r++)
        w[r] = *(const float4*)(beta + (size_t)(grow0 + r) * N + c0);

    float csum0 = 0.f, csum1 = 0.f, csum2 = 0.f, csum3 = 0.f;
    #pragma unroll
    for (int r = 0; r < RB; r++) {
        csum0 += w[r].x; csum1 += w[r].y; csum2 += w[r].z; csum3 += w[r].w;
    }
    *(float4*)(partial + ((size_t)b * chunksPerB + chunk) * N + c0) =
        make_float4(csum0, csum1, csum2, csum3);
    #pragma unroll
    for (int r = 0; r < RB; r++)
        #pragma unroll
        for (int c = 0; c < 6; c++)
            acc[r][c] += w[r].x*s[c].x + w[r].y*s[c].y + w[r].z*s[c].z + w[r].w*s[c].w;
}

__global__ __launch_bounds__(256) void fused_beta_kernel(
        const float* __restrict__ beta,
        const float* __restrict__ Splanes,
        float* __restrict__ T,
        float* __restrict__ partial,  // B * (N/RB) * N
        int B, int N, int BN) {
    int tid = threadIdx.x;
    int grow0 = blockIdx.x * RB;
    int b = grow0 / N;
    int chunksPerB = N / RB;
    int chunk = (grow0 - b * N) / RB;

    float acc[RB][6];
    #pragma unroll
    for (int r = 0; r < RB; r++)
        #pragma unroll
        for (int c = 0; c < 6; c++) acc[r][c] = 0.0f;

    if (N == 2048) {
        // straight-line both tiles: all loads issued before compute (ILP)
        int c0 = 4 * tid;
        int c1 = 1024 + 4 * tid;
        float4 s0[6], w0[RB], s1[6], w1[RB];
        #pragma unroll
        for (int c = 0; c < 6; c++)
            s0[c] = *(const float4*)(Splanes + (size_t)c * BN + (size_t)b * N + c0);
        #pragma unroll
        for (int r = 0; r < RB; r++)
            w0[r] = *(const float4*)(beta + (size_t)(grow0 + r) * N + c0);
        #pragma unroll
        for (int c = 0; c < 6; c++)
            s1[c] = *(const float4*)(Splanes + (size_t)c * BN + (size_t)b * N + c1);
        #pragma unroll
        for (int r = 0; r < RB; r++)
            w1[r] = *(const float4*)(beta + (size_t)(grow0 + r) * N + c1);

        {
            float csum0=0.f,csum1=0.f,csum2=0.f,csum3=0.f;
            #pragma unroll
            for (int r = 0; r < RB; r++) { csum0+=w0[r].x; csum1+=w0[r].y; csum2+=w0[r].z; csum3+=w0[r].w; }
            *(float4*)(partial + ((size_t)b * chunksPerB + chunk) * N + c0) =
                make_float4(csum0,csum1,csum2,csum3);
            #pragma unroll
            for (int r = 0; r < RB; r++)
                #pragma unroll
                for (int c = 0; c < 6; c++)
                    acc[r][c] += w0[r].x*s0[c].x + w0[r].y*s0[c].y + w0[r].z*s0[c].z + w0[r].w*s0[c].w;
        }
        {
            float csum0=0.f,csum1=0.f,csum2=0.f,csum3=0.f;
            #pragma unroll
            for (int r = 0; r < RB; r++) { csum0+=w1[r].x; csum1+=w1[r].y; csum2+=w1[r].z; csum3+=w1[r].w; }
            *(float4*)(partial + ((size_t)b * chunksPerB + chunk) * N + c1) =
                make_float4(csum0,csum1,csum2,csum3);
            #pragma unroll
            for (int r = 0; r < RB; r++)
                #pragma unroll
                for (int c = 0; c < 6; c++)
                    acc[r][c] += w1[r].x*s1[c].x + w1[r].y*s1[c].y + w1[r].z*s1[c].z + w1[r].w*s1[c].w;
        }
    } else {
        int jtiles = N / 1024;
        for (int jt = 0; jt < jtiles; jt++)
            beta_tile(beta, Splanes, partial, grow0, b, N, BN,
                      chunksPerB, chunk, jt * 1024 + 4 * tid, acc);
    }

    // ---- LDS transpose reduction: 256 threads x 48 values -> 48 sums ----
    __shared__ float red[256][48];
    __shared__ float red2[4][48];
    #pragma unroll
    for (int r = 0; r < RB; r++)
        #pragma unroll
        for (int c = 0; c < 6; c++)
            red[tid][r * 6 + c] = acc[r][c];
    __syncthreads();
    if (tid < 192) {
        int v = tid % 48, grp = tid / 48;
        float s = 0.0f;
        #pragma unroll 8
        for (int r = 0; r < 64; r++) s += red[grp * 64 + r][v];
        red2[grp][v] = s;
    }
    __syncthreads();
    if (tid < 48) {
        float v = red2[0][tid] + red2[1][tid] + red2[2][tid] + red2[3][tid];
        T[(size_t)grow0 * 6 + tid] = v;
    }
}

// ---------- kernel 3: finalize (128 blocks, 32 pts, float4 col-sum) ----------
__global__ __launch_bounds__(256) void finalize_kernel(
        const float* __restrict__ Sp,
        const float* __restrict__ Sq,
        const float* __restrict__ phi,
        const float* __restrict__ T,
        const float* __restrict__ partial, // B*(N/RB)*N
        float* __restrict__ out,
        int B, int N) {
    int tid  = threadIdx.x;
    int p0   = blockIdx.x * 32;     // 32 points per block
    int BN   = B * N;
    int b    = p0 / N;
    int i0   = p0 - b * N;
    int chunks = N / RB;            // 256

    __shared__ float4 redc[32][8];  // [group][col-quad]
    __shared__ float sp_s[288], sq_s[288], ph_s[96], t_s[192];
    __shared__ float o1_s[288], o2_s[288];

    // --- float4 column-sum: 32 groups x 8 chunks each, 8 col-quads ---
    {
        int m = tid & 7;            // col-quad 0..7 (32 cols)
        int g = tid >> 3;           // group 0..31
        int cpg = chunks / 32;      // 8
        float4 a = make_float4(0.f, 0.f, 0.f, 0.f);
        const float4* pp = (const float4*)(partial + ((size_t)b * chunks + g * cpg) * N + i0) + m;
        int stepq = N >> 2;
        #pragma unroll
        for (int k = 0; k < 8; k++) {
            float4 v = *pp; pp += stepq;
            a.x += v.x; a.y += v.y; a.z += v.z; a.w += v.w;
        }
        redc[g][m] = a;
    }

    // --- stage per-point inputs (coalesced float4) ---
    {
        const float4* s1 = (const float4*)(Sp + (size_t)p0 * 9);
        const float4* s2 = (const float4*)(Sq + (size_t)p0 * 9);
        if (tid < 72) { ((float4*)sp_s)[tid] = s1[tid]; ((float4*)sq_s)[tid] = s2[tid]; }
        const float4* s3 = (const float4*)(phi + (size_t)p0 * 3);
        if (tid < 24) ((float4*)ph_s)[tid] = s3[tid];
        const float4* s4 = (const float4*)(T + (size_t)p0 * 6);
        if (tid < 48) ((float4*)t_s)[tid] = s4[tid];
    }
    __syncthreads();

    if (tid < 32) {
        float cs = 0.0f;
        #pragma unroll
        for (int g = 0; g < 32; g++) {
            const float* rc = (const float*)&redc[g][tid >> 2];
            cs += rc[tid & 3];
        }

        float m[3][3], lp[3][3], lq[3][3];
        #pragma unroll
        for (int i = 0; i < 3; i++)
            #pragma unroll
            for (int j = 0; j < 3; j++) m[i][j] = sq_s[tid*9 + i*3 + j];
        m[0][0] += EPS_REG; m[1][1] += EPS_REG; m[2][2] += EPS_REG;
        sym_inv3(m, lq);
        #pragma unroll
        for (int i = 0; i < 3; i++)
            #pragma unroll
            for (int j = 0; j < 3; j++) m[i][j] = sp_s[tid*9 + i*3 + j];
        m[0][0] += EPS_REG; m[1][1] += EPS_REG; m[2][2] += EPS_REG;
        sym_inv3(m, lp);

        float R[3][3];
        rodrigues(ph_s[tid*3], ph_s[tid*3+1], ph_s[tid*3+2], R);

        const float* tp = t_s + tid * 6;
        float Tm[3][3] = {{tp[0],tp[1],tp[2]},{tp[1],tp[3],tp[4]},{tp[2],tp[4],tp[5]}};

        float U[3][3], M[3][3];
        #pragma unroll
        for (int ii = 0; ii < 3; ii++)
            #pragma unroll
            for (int jj = 0; jj < 3; jj++)
                U[ii][jj] = R[ii][0]*Tm[0][jj] + R[ii][1]*Tm[1][jj] + R[ii][2]*Tm[2][jj];
        #pragma unroll
        for (int ii = 0; ii < 3; ii++)
            #pragma unroll
            for (int jj = 0; jj < 3; jj++) {
                float min_ij = U[ii][0]*R[jj][0] + U[ii][1]*R[jj][1] + U[ii][2]*R[jj][2];
                M[ii][jj] = lp[ii][jj] + min_ij + cs * lq[ii][jj];
            }
        float A[3][3];
        #pragma unroll
        for (int ii = 0; ii < 3; ii++)
            #pragma unroll
            for (int jj = 0; jj < 3; jj++) A[ii][jj] = 0.5f * (M[ii][jj] + M[jj][ii]);

        float V[3][3] = {{1,0,0},{0,1,0},{0,0,1}};
        #pragma unroll
        for (int sweep = 0; sweep < 6; sweep++) {
            jrot(A, V, 0, 1);
            jrot(A, V, 0, 2);
            jrot(A, V, 1, 2);
        }
        float w0 = fmaxf(A[0][0], MIN_EIG_F);
        float w1 = fmaxf(A[1][1], MIN_EIG_F);
        float w2 = fmaxf(A[2][2], MIN_EIG_F);
        float iw0 = 1.0f/w0, iw1 = 1.0f/w1, iw2 = 1.0f/w2;

        #pragma unroll
        for (int ii = 0; ii < 3; ii++)
            #pragma unroll
            for (int jj = 0; jj < 3; jj++) {
                o1_s[tid*9 + ii*3 + jj] = V[ii][0]*w0*V[jj][0] + V[ii][1]*w1*V[jj][1] + V[ii][2]*w2*V[jj][2];
                o2_s[tid*9 + ii*3 + jj] = V[ii][0]*iw0*V[jj][0] + V[ii][1]*iw1*V[jj][1] + V[ii][2]*iw2*V[jj][2];
            }
    }
    __syncthreads();

    float4* d1 = (float4*)(out + (size_t)p0 * 9);
    float4* d2 = (float4*)(out + (size_t)BN * 9 + (size_t)p0 * 9);
    if (tid < 72) { d1[tid] = ((float4*)o1_s)[tid]; d2[tid] = ((float4*)o2_s)[tid]; }
}

extern "C" void kernel_launch(void* const* d_in, const int* in_sizes, int n_in,
                              void* d_out, int out_size, void* d_ws, size_t ws_size,
                              hipStream_t stream) {
    const float* Sp   = (const float*)d_in[0];
    const float* Sq   = (const float*)d_in[1];
    const float* phi  = (const float*)d_in[2];
    const float* beta = (const float*)d_in[3];

    int BN = in_sizes[2] / 3;                 // B*N
    int N  = (int)((long long)in_sizes[3] / BN);
    int B  = BN / N;

    float* ws = (float*)d_ws;
    float* Splanes = ws;                        // 6*BN
    float* T       = Splanes + (size_t)BN * 6;  // BN*6
    float* partial = T + (size_t)BN * 6;        // B*(N/RB)*N

    float* outf = (float*)d_out;

    precompute_S_kernel<<<BN / 64, 64, 0, stream>>>(Sq, phi, Splanes, BN);

    fused_beta_kernel<<<BN / RB, 256, 0, stream>>>(beta, Splanes, T, partial, B, N, BN);

    finalize_kernel<<<BN / 32, 256, 0, stream>>>(Sp, Sq, phi, T, partial, outf, B, N);
}